// Round 3
// baseline (500.888 us; speedup 1.0000x reference)
//
#include <hip/hip_runtime.h>
#include <math.h>

// Problem constants (reference: B=8, N=2048, C=256, W=256)
#define Bb 8
#define Nn 2048
#define Cc 256
#define Ww 256
#define Mtot (Bb*Nn)   // 16384

typedef __attribute__((ext_vector_type(8))) short bf16x8;
typedef __attribute__((ext_vector_type(4))) float f32x4;

__device__ __forceinline__ ushort bf16_rne(float f) {
    uint u = __float_as_uint(f);
    return (ushort)((u + 0x7FFFu + ((u >> 16) & 1u)) >> 16);
}
__device__ __forceinline__ float bf16_to_f32(ushort h) {
    return __uint_as_float(((uint)h) << 16);
}

// ---------------------------------------------------------------------------
// Kernel 1: fused QKV projection. r = relu(x·Wᵀ + b).
// q,k are emitted as SPLIT bf16 (hi + lo residual) for the MFMA scores kernel;
// v stays fp32 for the fp32 PV kernel. q fp32 is NOT stored (PV reconstructs
// q = hi + lo, rel err 2^-18).
// grid (128, 12), block 256. blockIdx.y: 0..3 -> q, 4..7 -> k, 8..11 -> v.
// ---------------------------------------------------------------------------
__global__ __launch_bounds__(256) void qkv_proj_kernel(
    const float* __restrict__ x,
    const float* __restrict__ Wq, const float* __restrict__ bq,
    const float* __restrict__ Wk, const float* __restrict__ bk,
    const float* __restrict__ Wv, const float* __restrict__ bv,
    float* __restrict__ v32,
    ushort* __restrict__ qhi, ushort* __restrict__ qlo,
    ushort* __restrict__ khi, ushort* __restrict__ klo)
{
    __shared__ float xs[16][132];   // [k][m], +4 pad
    __shared__ float ws[16][68];    // [k][w]

    const int tid = threadIdx.x;
    const int tn = tid & 15;
    const int tm = tid >> 4;
    const int m0 = blockIdx.x * 128;
    const int nt = blockIdx.y;
    const int which = nt >> 2;
    const int w0 = (nt & 3) * 64;

    const float* Wm = (which == 0) ? Wq : ((which == 1) ? Wk : Wv);
    const float* bm = (which == 0) ? bq : ((which == 1) ? bk : bv);

    float acc[8][4];
    #pragma unroll
    for (int i = 0; i < 8; ++i)
        #pragma unroll
        for (int j = 0; j < 4; ++j) acc[i][j] = 0.f;

    for (int kc = 0; kc < Cc; kc += 16) {
        #pragma unroll
        for (int l = 0; l < 2; ++l) {
            int s = tid + l * 256;
            int r = s >> 2, c4 = s & 3;
            float4 tv = *(const float4*)(x + (size_t)(m0 + r) * Cc + kc + c4 * 4);
            xs[c4*4+0][r] = tv.x; xs[c4*4+1][r] = tv.y;
            xs[c4*4+2][r] = tv.z; xs[c4*4+3][r] = tv.w;
        }
        {
            int r = tid >> 2, c4 = tid & 3;
            float4 tv = *(const float4*)(Wm + (size_t)(w0 + r) * Cc + kc + c4 * 4);
            ws[c4*4+0][r] = tv.x; ws[c4*4+1][r] = tv.y;
            ws[c4*4+2][r] = tv.z; ws[c4*4+3][r] = tv.w;
        }
        __syncthreads();
        #pragma unroll
        for (int kk = 0; kk < 16; ++kk) {
            float4 a0 = *(const float4*)&xs[kk][tm*4];
            float4 a1 = *(const float4*)&xs[kk][tm*4 + 64];
            float4 b0 = *(const float4*)&ws[kk][tn*4];
            float a[8] = {a0.x,a0.y,a0.z,a0.w,a1.x,a1.y,a1.z,a1.w};
            float b[4] = {b0.x,b0.y,b0.z,b0.w};
            #pragma unroll
            for (int i = 0; i < 8; ++i)
                #pragma unroll
                for (int j = 0; j < 4; ++j) acc[i][j] += a[i] * b[j];
        }
        __syncthreads();
    }

    float4 bias = *(const float4*)(bm + w0 + tn*4);
    #pragma unroll
    for (int i = 0; i < 8; ++i) {
        int m = m0 + tm*4 + (i & 3) + (i >> 2) * 64;
        float rr0 = fmaxf(acc[i][0] + bias.x, 0.f);
        float rr1 = fmaxf(acc[i][1] + bias.y, 0.f);
        float rr2 = fmaxf(acc[i][2] + bias.z, 0.f);
        float rr3 = fmaxf(acc[i][3] + bias.w, 0.f);
        size_t o = (size_t)m * Ww + w0 + tn*4;
        if (which == 2) {
            float4 r; r.x = rr0; r.y = rr1; r.z = rr2; r.w = rr3;
            *(float4*)(v32 + o) = r;
        } else {
            ushort4 h, l;
            h.x = bf16_rne(rr0); l.x = bf16_rne(rr0 - bf16_to_f32(h.x));
            h.y = bf16_rne(rr1); l.y = bf16_rne(rr1 - bf16_to_f32(h.y));
            h.z = bf16_rne(rr2); l.z = bf16_rne(rr2 - bf16_to_f32(h.z));
            h.w = bf16_rne(rr3); l.w = bf16_rne(rr3 - bf16_to_f32(h.w));
            ushort* hp = (which == 0) ? qhi : khi;
            ushort* lp = (which == 0) ? qlo : klo;
            *(ushort4*)(hp + o) = h;
            *(ushort4*)(lp + o) = l;
        }
    }
}

// ---------------------------------------------------------------------------
// Kernel 2: ST[b][j][i] = scale * sum_w k[b,j,w] * q[b,i,w]  via split-bf16
// MFMA (hi*hi + hi*lo + lo*hi; dropped lo*lo ~ 2^-18 relative).
// D = A·B: A[j][w] = k rows (M=j), B[w][i] = qᵀ (N=i), K = w.
// mfma_f32_16x16x32_bf16 fragment layout (std CDNA): lane l holds
//   A[l&15][8*(l>>4)+jj], B[8*(l>>4)+jj][l&15]  -> both are contiguous 16B
//   reads from row-major [row][K] tiles.
// C/D (m89-verified): col = lane&15, row = (lane>>4)*4 + reg.
// Block 128j x 128i, 4 waves in 2x2 (each 64x64 = 4x4 frags). K-step 32.
// LDS tiles [128][32] bf16, chunk-XOR swizzle g^=((r>>1)&3) -> <=2-way
// conflicts (free, m136).
// ---------------------------------------------------------------------------
__global__ __launch_bounds__(256) void scores_mfma_kernel(
    const ushort* __restrict__ qhi, const ushort* __restrict__ qlo,
    const ushort* __restrict__ khi, const ushort* __restrict__ klo,
    float* __restrict__ st)
{
    __shared__ ushort lkh[4096], lkl[4096], lqh[4096], lql[4096];

    const int tid = threadIdx.x;
    const int i0 = blockIdx.x * 128;
    const int j0 = blockIdx.y * 128;
    const int b  = blockIdx.z;

    const ushort* kh = khi + ((size_t)b * Nn + j0) * Ww;
    const ushort* kl = klo + ((size_t)b * Nn + j0) * Ww;
    const ushort* qh = qhi + ((size_t)b * Nn + i0) * Ww;
    const ushort* ql = qlo + ((size_t)b * Nn + i0) * Ww;

    const int wave = tid >> 6, lane = tid & 63;
    const int wy = wave >> 1, wx = wave & 1;    // j / i 64-sub-tile
    const int lrow = lane & 15, lg = lane >> 4; // fragment row, 8-elem k-chunk

    f32x4 acc[4][4];
    #pragma unroll
    for (int a = 0; a < 4; ++a)
        #pragma unroll
        for (int c = 0; c < 4; ++c) acc[a][c] = (f32x4){0.f, 0.f, 0.f, 0.f};

    const int cg = tid & 3;          // k-chunk this thread stages
    const int cr0 = tid >> 2;        // rows 0..63, second pass +64

    for (int kc = 0; kc < Ww; kc += 32) {
        #pragma unroll
        for (int h = 0; h < 2; ++h) {
            int r = cr0 + h * 64;
            int gg = cg ^ ((r >> 1) & 3);
            int li = r * 32 + gg * 8;
            size_t go = (size_t)r * Ww + kc + cg * 8;
            *(bf16x8*)&lkh[li] = *(const bf16x8*)(kh + go);
            *(bf16x8*)&lkl[li] = *(const bf16x8*)(kl + go);
            *(bf16x8*)&lqh[li] = *(const bf16x8*)(qh + go);
            *(bf16x8*)&lql[li] = *(const bf16x8*)(ql + go);
        }
        __syncthreads();

        bf16x8 ah[4], al[4], bh[4], bl[4];
        #pragma unroll
        for (int t = 0; t < 4; ++t) {
            int ra = wy * 64 + t * 16 + lrow;
            int ia = ra * 32 + ((lg ^ ((ra >> 1) & 3)) * 8);
            ah[t] = *(const bf16x8*)&lkh[ia];
            al[t] = *(const bf16x8*)&lkl[ia];
            int rb = wx * 64 + t * 16 + lrow;
            int ib = rb * 32 + ((lg ^ ((rb >> 1) & 3)) * 8);
            bh[t] = *(const bf16x8*)&lqh[ib];
            bl[t] = *(const bf16x8*)&lql[ib];
        }
        #pragma unroll
        for (int jt = 0; jt < 4; ++jt)
            #pragma unroll
            for (int it = 0; it < 4; ++it) {
                acc[jt][it] = __builtin_amdgcn_mfma_f32_16x16x32_bf16(ah[jt], bh[it], acc[jt][it], 0, 0, 0);
                acc[jt][it] = __builtin_amdgcn_mfma_f32_16x16x32_bf16(ah[jt], bl[it], acc[jt][it], 0, 0, 0);
                acc[jt][it] = __builtin_amdgcn_mfma_f32_16x16x32_bf16(al[jt], bh[it], acc[jt][it], 0, 0, 0);
            }
        __syncthreads();
    }

    const float scale = 0.02209708691207961f;  // 1/sqrt(2048)
    float* stb = st + (size_t)b * Nn * Nn;
    #pragma unroll
    for (int jt = 0; jt < 4; ++jt) {
        int jbase = j0 + wy * 64 + jt * 16 + lg * 4;
        #pragma unroll
        for (int it = 0; it < 4; ++it) {
            int i = i0 + wx * 64 + it * 16 + lrow;
            #pragma unroll
            for (int rg = 0; rg < 4; ++rg)
                stb[(size_t)(jbase + rg) * Nn + i] = acc[jt][it][rg] * scale;
        }
    }
}

// ---------------------------------------------------------------------------
// Kernel 3: in-place row softmax of ST (rows = softmax axis i).
// grid (2048, 8), block 256.
// ---------------------------------------------------------------------------
__global__ __launch_bounds__(256) void softmax_kernel(float* __restrict__ st)
{
    const int j = blockIdx.x;
    const int b = blockIdx.y;
    float* row = st + (size_t)b * Nn * Nn + (size_t)j * Nn;
    const int tid = threadIdx.x;

    float4 v0 = *(const float4*)(row + tid * 4);
    float4 v1 = *(const float4*)(row + 1024 + tid * 4);

    float vmax = fmaxf(fmaxf(fmaxf(v0.x, v0.y), fmaxf(v0.z, v0.w)),
                       fmaxf(fmaxf(v1.x, v1.y), fmaxf(v1.z, v1.w)));
    #pragma unroll
    for (int off = 32; off > 0; off >>= 1)
        vmax = fmaxf(vmax, __shfl_xor(vmax, off));

    __shared__ float redm[4];
    __shared__ float reds[4];
    const int wid = tid >> 6, lane = tid & 63;
    if (lane == 0) redm[wid] = vmax;
    __syncthreads();
    vmax = fmaxf(fmaxf(redm[0], redm[1]), fmaxf(redm[2], redm[3]));

    float e[8];
    e[0] = __expf(v0.x - vmax); e[1] = __expf(v0.y - vmax);
    e[2] = __expf(v0.z - vmax); e[3] = __expf(v0.w - vmax);
    e[4] = __expf(v1.x - vmax); e[5] = __expf(v1.y - vmax);
    e[6] = __expf(v1.z - vmax); e[7] = __expf(v1.w - vmax);

    float sum = ((e[0] + e[1]) + (e[2] + e[3])) + ((e[4] + e[5]) + (e[6] + e[7]));
    #pragma unroll
    for (int off = 32; off > 0; off >>= 1)
        sum += __shfl_xor(sum, off);
    if (lane == 0) reds[wid] = sum;
    __syncthreads();
    sum = (reds[0] + reds[1]) + (reds[2] + reds[3]);

    const float inv = 1.0f / sum;
    float4 o0, o1;
    o0.x = e[0]*inv; o0.y = e[1]*inv; o0.z = e[2]*inv; o0.w = e[3]*inv;
    o1.x = e[4]*inv; o1.y = e[5]*inv; o1.z = e[6]*inv; o1.w = e[7]*inv;
    *(float4*)(row + tid * 4) = o0;
    *(float4*)(row + 1024 + tid * 4) = o1;
}

// ---------------------------------------------------------------------------
// Kernel 4: out[b,i,w] = sum_j ST[b,j,i] * v[b,j,w] + q[b,i,w]   (fp32 VALU)
// q reconstructed from split bf16 (hi+lo, rel err 2^-18).
// grid (4, 16, 8), block 256. Tile 128(i) x 64(w), BK=16.
// ---------------------------------------------------------------------------
__global__ __launch_bounds__(256) void pv_kernel(
    const float* __restrict__ st, const float* __restrict__ v,
    const ushort* __restrict__ qhi, const ushort* __restrict__ qlo,
    float* __restrict__ out)
{
    __shared__ float As[16][128];  // [kj][i]
    __shared__ float Bs[16][64];   // [kj][w]

    const int tid = threadIdx.x;
    const int tn = tid & 15;   // w
    const int tm = tid >> 4;   // i
    const int w0 = blockIdx.x * 64;
    const int i0 = blockIdx.y * 128;
    const int b  = blockIdx.z;
    const float* stb = st + (size_t)b * Nn * Nn;
    const float* vb  = v  + (size_t)b * Nn * Ww;

    float acc[8][4];
    #pragma unroll
    for (int i = 0; i < 8; ++i)
        #pragma unroll
        for (int j = 0; j < 4; ++j) acc[i][j] = 0.f;

    for (int kc = 0; kc < Nn; kc += 16) {
        #pragma unroll
        for (int l = 0; l < 2; ++l) {
            int s = tid + l * 256;
            int kj = s >> 5, c4 = s & 31;
            float4 tv = *(const float4*)(stb + (size_t)(kc + kj) * Nn + i0 + c4 * 4);
            *(float4*)&As[kj][c4 * 4] = tv;
        }
        {
            int kj = tid >> 4, c4 = tid & 15;
            float4 tv = *(const float4*)(vb + (size_t)(kc + kj) * Ww + w0 + c4 * 4);
            *(float4*)&Bs[kj][c4 * 4] = tv;
        }
        __syncthreads();
        #pragma unroll
        for (int kk = 0; kk < 16; ++kk) {
            float4 a0 = *(const float4*)&As[kk][tm*4];
            float4 a1 = *(const float4*)&As[kk][tm*4 + 64];
            float4 b0 = *(const float4*)&Bs[kk][tn*4];
            float a[8] = {a0.x,a0.y,a0.z,a0.w,a1.x,a1.y,a1.z,a1.w};
            float bv4[4] = {b0.x,b0.y,b0.z,b0.w};
            #pragma unroll
            for (int ii = 0; ii < 8; ++ii)
                #pragma unroll
                for (int jj = 0; jj < 4; ++jj) acc[ii][jj] += a[ii] * bv4[jj];
        }
        __syncthreads();
    }

    #pragma unroll
    for (int ii = 0; ii < 8; ++ii) {
        int i = i0 + tm*4 + (ii & 3) + (ii >> 2) * 64;
        size_t gidx = (size_t)(b * Nn + i) * Ww + w0 + tn * 4;
        ushort4 qh4 = *(const ushort4*)(qhi + gidx);
        ushort4 ql4 = *(const ushort4*)(qlo + gidx);
        float4 r;
        r.x = acc[ii][0] + bf16_to_f32(qh4.x) + bf16_to_f32(ql4.x);
        r.y = acc[ii][1] + bf16_to_f32(qh4.y) + bf16_to_f32(ql4.y);
        r.z = acc[ii][2] + bf16_to_f32(qh4.z) + bf16_to_f32(ql4.z);
        r.w = acc[ii][3] + bf16_to_f32(qh4.w) + bf16_to_f32(ql4.w);
        *(float4*)(out + gidx) = r;
    }
}

// ---------------------------------------------------------------------------
// Launch. ws layout: v32 f32 [16MB] | qhi,qlo,khi,klo bf16 [4x8MB] | ST f32
// [128MB]  -> total 176 MiB (same footprint as the fp32 baseline).
// ---------------------------------------------------------------------------
extern "C" void kernel_launch(void* const* d_in, const int* in_sizes, int n_in,
                              void* d_out, int out_size, void* d_ws, size_t ws_size,
                              hipStream_t stream) {
    const float* x  = (const float*)d_in[0];
    const float* Wq = (const float*)d_in[1];
    const float* bq = (const float*)d_in[2];
    const float* Wk = (const float*)d_in[3];
    const float* bk = (const float*)d_in[4];
    const float* Wv = (const float*)d_in[5];
    const float* bv = (const float*)d_in[6];
    // d_in[7] = valid_len (unused by the reference forward)
    float* out = (float*)d_out;

    float*  v32 = (float*)d_ws;
    ushort* qhi = (ushort*)(v32 + (size_t)Mtot * Ww);
    ushort* qlo = qhi + (size_t)Mtot * Ww;
    ushort* khi = qlo + (size_t)Mtot * Ww;
    ushort* klo = khi + (size_t)Mtot * Ww;
    float*  st  = (float*)(klo + (size_t)Mtot * Ww);

    qkv_proj_kernel<<<dim3(128, 12), 256, 0, stream>>>(x, Wq, bq, Wk, bk, Wv, bv,
                                                       v32, qhi, qlo, khi, klo);
    scores_mfma_kernel<<<dim3(16, 16, 8), 256, 0, stream>>>(qhi, qlo, khi, klo, st);
    softmax_kernel<<<dim3(Nn, Bb), 256, 0, stream>>>(st);
    pv_kernel<<<dim3(4, 16, 8), 256, 0, stream>>>(st, v32, qhi, qlo, out);
}

// Round 4
// 374.378 us; speedup vs baseline: 1.3379x; 1.3379x over previous
//
#include <hip/hip_runtime.h>
#include <math.h>

// Problem constants (reference: B=8, N=2048, C=256, W=256)
#define Bb 8
#define Nn 2048
#define Cc 256
#define Ww 256
#define Mtot (Bb*Nn)   // 16384

typedef __attribute__((ext_vector_type(8))) short bf16x8;
typedef __attribute__((ext_vector_type(4))) float f32x4;

__device__ __forceinline__ ushort bf16_rne(float f) {
    uint u = __float_as_uint(f);
    return (ushort)((u + 0x7FFFu + ((u >> 16) & 1u)) >> 16);
}
__device__ __forceinline__ float bf16_to_f32(ushort h) {
    return __uint_as_float(((uint)h) << 16);
}

// ---------------------------------------------------------------------------
// Kernel 1: fused QKV projection. r = relu(x·Wᵀ + b).  (unchanged, proven)
// q,k emitted as SPLIT bf16 (hi + lo residual); v stays fp32 (vt_kernel
// transposes/splits it afterwards). PV reconstructs q = hi + lo.
// grid (128, 12), block 256. blockIdx.y: 0..3 -> q, 4..7 -> k, 8..11 -> v.
// ---------------------------------------------------------------------------
__global__ __launch_bounds__(256) void qkv_proj_kernel(
    const float* __restrict__ x,
    const float* __restrict__ Wq, const float* __restrict__ bq,
    const float* __restrict__ Wk, const float* __restrict__ bk,
    const float* __restrict__ Wv, const float* __restrict__ bv,
    float* __restrict__ v32,
    ushort* __restrict__ qhi, ushort* __restrict__ qlo,
    ushort* __restrict__ khi, ushort* __restrict__ klo)
{
    __shared__ float xs[16][132];   // [k][m], +4 pad
    __shared__ float ws[16][68];    // [k][w]

    const int tid = threadIdx.x;
    const int tn = tid & 15;
    const int tm = tid >> 4;
    const int m0 = blockIdx.x * 128;
    const int nt = blockIdx.y;
    const int which = nt >> 2;
    const int w0 = (nt & 3) * 64;

    const float* Wm = (which == 0) ? Wq : ((which == 1) ? Wk : Wv);
    const float* bm = (which == 0) ? bq : ((which == 1) ? bk : bv);

    float acc[8][4];
    #pragma unroll
    for (int i = 0; i < 8; ++i)
        #pragma unroll
        for (int j = 0; j < 4; ++j) acc[i][j] = 0.f;

    for (int kc = 0; kc < Cc; kc += 16) {
        #pragma unroll
        for (int l = 0; l < 2; ++l) {
            int s = tid + l * 256;
            int r = s >> 2, c4 = s & 3;
            float4 tv = *(const float4*)(x + (size_t)(m0 + r) * Cc + kc + c4 * 4);
            xs[c4*4+0][r] = tv.x; xs[c4*4+1][r] = tv.y;
            xs[c4*4+2][r] = tv.z; xs[c4*4+3][r] = tv.w;
        }
        {
            int r = tid >> 2, c4 = tid & 3;
            float4 tv = *(const float4*)(Wm + (size_t)(w0 + r) * Cc + kc + c4 * 4);
            ws[c4*4+0][r] = tv.x; ws[c4*4+1][r] = tv.y;
            ws[c4*4+2][r] = tv.z; ws[c4*4+3][r] = tv.w;
        }
        __syncthreads();
        #pragma unroll
        for (int kk = 0; kk < 16; ++kk) {
            float4 a0 = *(const float4*)&xs[kk][tm*4];
            float4 a1 = *(const float4*)&xs[kk][tm*4 + 64];
            float4 b0 = *(const float4*)&ws[kk][tn*4];
            float a[8] = {a0.x,a0.y,a0.z,a0.w,a1.x,a1.y,a1.z,a1.w};
            float b[4] = {b0.x,b0.y,b0.z,b0.w};
            #pragma unroll
            for (int i = 0; i < 8; ++i)
                #pragma unroll
                for (int j = 0; j < 4; ++j) acc[i][j] += a[i] * b[j];
        }
        __syncthreads();
    }

    float4 bias = *(const float4*)(bm + w0 + tn*4);
    #pragma unroll
    for (int i = 0; i < 8; ++i) {
        int m = m0 + tm*4 + (i & 3) + (i >> 2) * 64;
        float rr0 = fmaxf(acc[i][0] + bias.x, 0.f);
        float rr1 = fmaxf(acc[i][1] + bias.y, 0.f);
        float rr2 = fmaxf(acc[i][2] + bias.z, 0.f);
        float rr3 = fmaxf(acc[i][3] + bias.w, 0.f);
        size_t o = (size_t)m * Ww + w0 + tn*4;
        if (which == 2) {
            float4 r; r.x = rr0; r.y = rr1; r.z = rr2; r.w = rr3;
            *(float4*)(v32 + o) = r;
        } else {
            ushort4 h, l;
            h.x = bf16_rne(rr0); l.x = bf16_rne(rr0 - bf16_to_f32(h.x));
            h.y = bf16_rne(rr1); l.y = bf16_rne(rr1 - bf16_to_f32(h.y));
            h.z = bf16_rne(rr2); l.z = bf16_rne(rr2 - bf16_to_f32(h.z));
            h.w = bf16_rne(rr3); l.w = bf16_rne(rr3 - bf16_to_f32(h.w));
            ushort* hp = (which == 0) ? qhi : khi;
            ushort* lp = (which == 0) ? qlo : klo;
            *(ushort4*)(hp + o) = h;
            *(ushort4*)(lp + o) = l;
        }
    }
}

// ---------------------------------------------------------------------------
// Kernel 2: ST[b][j][i] = scale * sum_w k[b,j,w]*q[b,i,w], split-bf16 MFMA.
// (unchanged, proven on HW round 3)
// ---------------------------------------------------------------------------
__global__ __launch_bounds__(256) void scores_mfma_kernel(
    const ushort* __restrict__ qhi, const ushort* __restrict__ qlo,
    const ushort* __restrict__ khi, const ushort* __restrict__ klo,
    float* __restrict__ st)
{
    __shared__ ushort lkh[4096], lkl[4096], lqh[4096], lql[4096];

    const int tid = threadIdx.x;
    const int i0 = blockIdx.x * 128;
    const int j0 = blockIdx.y * 128;
    const int b  = blockIdx.z;

    const ushort* kh = khi + ((size_t)b * Nn + j0) * Ww;
    const ushort* kl = klo + ((size_t)b * Nn + j0) * Ww;
    const ushort* qh = qhi + ((size_t)b * Nn + i0) * Ww;
    const ushort* ql = qlo + ((size_t)b * Nn + i0) * Ww;

    const int wave = tid >> 6, lane = tid & 63;
    const int wy = wave >> 1, wx = wave & 1;
    const int lrow = lane & 15, lg = lane >> 4;

    f32x4 acc[4][4];
    #pragma unroll
    for (int a = 0; a < 4; ++a)
        #pragma unroll
        for (int c = 0; c < 4; ++c) acc[a][c] = (f32x4){0.f, 0.f, 0.f, 0.f};

    const int cg = tid & 3;
    const int cr0 = tid >> 2;

    for (int kc = 0; kc < Ww; kc += 32) {
        #pragma unroll
        for (int h = 0; h < 2; ++h) {
            int r = cr0 + h * 64;
            int gg = cg ^ ((r >> 1) & 3);
            int li = r * 32 + gg * 8;
            size_t go = (size_t)r * Ww + kc + cg * 8;
            *(bf16x8*)&lkh[li] = *(const bf16x8*)(kh + go);
            *(bf16x8*)&lkl[li] = *(const bf16x8*)(kl + go);
            *(bf16x8*)&lqh[li] = *(const bf16x8*)(qh + go);
            *(bf16x8*)&lql[li] = *(const bf16x8*)(ql + go);
        }
        __syncthreads();

        bf16x8 ah[4], al[4], bh[4], bl[4];
        #pragma unroll
        for (int t = 0; t < 4; ++t) {
            int ra = wy * 64 + t * 16 + lrow;
            int ia = ra * 32 + ((lg ^ ((ra >> 1) & 3)) * 8);
            ah[t] = *(const bf16x8*)&lkh[ia];
            al[t] = *(const bf16x8*)&lkl[ia];
            int rb = wx * 64 + t * 16 + lrow;
            int ib = rb * 32 + ((lg ^ ((rb >> 1) & 3)) * 8);
            bh[t] = *(const bf16x8*)&lqh[ib];
            bl[t] = *(const bf16x8*)&lql[ib];
        }
        #pragma unroll
        for (int jt = 0; jt < 4; ++jt)
            #pragma unroll
            for (int it = 0; it < 4; ++it) {
                acc[jt][it] = __builtin_amdgcn_mfma_f32_16x16x32_bf16(ah[jt], bh[it], acc[jt][it], 0, 0, 0);
                acc[jt][it] = __builtin_amdgcn_mfma_f32_16x16x32_bf16(ah[jt], bl[it], acc[jt][it], 0, 0, 0);
                acc[jt][it] = __builtin_amdgcn_mfma_f32_16x16x32_bf16(al[jt], bh[it], acc[jt][it], 0, 0, 0);
            }
        __syncthreads();
    }

    const float scale = 0.02209708691207961f;  // 1/sqrt(2048)
    float* stb = st + (size_t)b * Nn * Nn;
    #pragma unroll
    for (int jt = 0; jt < 4; ++jt) {
        int jbase = j0 + wy * 64 + jt * 16 + lg * 4;
        #pragma unroll
        for (int it = 0; it < 4; ++it) {
            int i = i0 + wx * 64 + it * 16 + lrow;
            #pragma unroll
            for (int rg = 0; rg < 4; ++rg)
                stb[(size_t)(jbase + rg) * Nn + i] = acc[jt][it][rg] * scale;
        }
    }
}

// ---------------------------------------------------------------------------
// Kernel 2.5 (NEW): vT split-transpose. v32[b][j][w] f32 -> vthi/vtlo[b][w][j]
// bf16 hi/lo. Classic LDS tile transpose, coalesced both sides.
// grid (32 jt, 4 wt, 8 b), block 256. Reuses khi/klo ws space (safe: runs
// after scores_mfma has consumed k).
// ---------------------------------------------------------------------------
__global__ __launch_bounds__(256) void vt_kernel(
    const float* __restrict__ v32,
    ushort* __restrict__ vthi, ushort* __restrict__ vtlo)
{
    __shared__ ushort Thi[64*66], Tlo[64*66];   // [w][j], stride 66 (odd-bank)
    const int tid = threadIdx.x;
    const int j0 = blockIdx.x * 64;
    const int w0 = blockIdx.y * 64;
    const int b  = blockIdx.z;
    const float* vb = v32 + (size_t)b * Nn * Ww;

    #pragma unroll
    for (int r = 0; r < 4; ++r) {
        int j  = (tid >> 4) + r * 16;
        int wl = (tid & 15) * 4;
        float4 tv = *(const float4*)(vb + (size_t)(j0 + j) * Ww + w0 + wl);
        float f[4] = {tv.x, tv.y, tv.z, tv.w};
        #pragma unroll
        for (int c = 0; c < 4; ++c) {
            ushort h = bf16_rne(f[c]);
            Thi[(wl + c) * 66 + j] = h;
            Tlo[(wl + c) * 66 + j] = bf16_rne(f[c] - bf16_to_f32(h));
        }
    }
    __syncthreads();
    {
        int wl = tid >> 2, jc = (tid & 3) * 16;
        size_t go = ((size_t)b * Ww + w0 + wl) * Nn + j0 + jc;
        uint tH[8], tL[8];
        #pragma unroll
        for (int u = 0; u < 8; ++u) {
            tH[u] = *(const uint*)&Thi[wl * 66 + jc + u * 2];
            tL[u] = *(const uint*)&Tlo[wl * 66 + jc + u * 2];
        }
        #pragma unroll
        for (int u = 0; u < 2; ++u) {
            uint4 hh; hh.x = tH[u*4+0]; hh.y = tH[u*4+1]; hh.z = tH[u*4+2]; hh.w = tH[u*4+3];
            uint4 ll; ll.x = tL[u*4+0]; ll.y = tL[u*4+1]; ll.z = tL[u*4+2]; ll.w = tL[u*4+3];
            *(uint4*)(vthi + go + u * 8) = hh;
            *(uint4*)(vtlo + go + u * 8) = ll;
        }
    }
}

// ---------------------------------------------------------------------------
// Kernel 3: in-place row softmax of ST (rows = softmax axis i). (unchanged)
// ---------------------------------------------------------------------------
__global__ __launch_bounds__(256) void softmax_kernel(float* __restrict__ st)
{
    const int j = blockIdx.x;
    const int b = blockIdx.y;
    float* row = st + (size_t)b * Nn * Nn + (size_t)j * Nn;
    const int tid = threadIdx.x;

    float4 v0 = *(const float4*)(row + tid * 4);
    float4 v1 = *(const float4*)(row + 1024 + tid * 4);

    float vmax = fmaxf(fmaxf(fmaxf(v0.x, v0.y), fmaxf(v0.z, v0.w)),
                       fmaxf(fmaxf(v1.x, v1.y), fmaxf(v1.z, v1.w)));
    #pragma unroll
    for (int off = 32; off > 0; off >>= 1)
        vmax = fmaxf(vmax, __shfl_xor(vmax, off));

    __shared__ float redm[4];
    __shared__ float reds[4];
    const int wid = tid >> 6, lane = tid & 63;
    if (lane == 0) redm[wid] = vmax;
    __syncthreads();
    vmax = fmaxf(fmaxf(redm[0], redm[1]), fmaxf(redm[2], redm[3]));

    float e[8];
    e[0] = __expf(v0.x - vmax); e[1] = __expf(v0.y - vmax);
    e[2] = __expf(v0.z - vmax); e[3] = __expf(v0.w - vmax);
    e[4] = __expf(v1.x - vmax); e[5] = __expf(v1.y - vmax);
    e[6] = __expf(v1.z - vmax); e[7] = __expf(v1.w - vmax);

    float sum = ((e[0] + e[1]) + (e[2] + e[3])) + ((e[4] + e[5]) + (e[6] + e[7]));
    #pragma unroll
    for (int off = 32; off > 0; off >>= 1)
        sum += __shfl_xor(sum, off);
    if (lane == 0) reds[wid] = sum;
    __syncthreads();
    sum = (reds[0] + reds[1]) + (reds[2] + reds[3]);

    const float inv = 1.0f / sum;
    float4 o0, o1;
    o0.x = e[0]*inv; o0.y = e[1]*inv; o0.z = e[2]*inv; o0.w = e[3]*inv;
    o1.x = e[4]*inv; o1.y = e[5]*inv; o1.z = e[6]*inv; o1.w = e[7]*inv;
    *(float4*)(row + tid * 4) = o0;
    *(float4*)(row + 1024 + tid * 4) = o1;
}

// ---------------------------------------------------------------------------
// Kernel 4 (NEW): PV via split-bf16 MFMA.
// out[b,i,w] = sum_j P[j][i]*v[j][w] + q[i][w];  P = softmaxed ST (fp32).
// D[m=i][n=w], K=j. A = P^T built on the fly (fp32 ST tile -> hi/lo bf16,
// transposed into LDS). B = vT (pre-transposed split bf16, [w][j]).
// Tile 64i x 256w (full W: ST stripe read ONCE -> no 4x refetch), BK=32.
// 512 thr = 8 waves, each 16i x 128w (1 A-frag, 8 B-frags, 24 MFMA/K-step).
// T14 async-stage: next-tile global loads issued between barrier and MFMA.
// grid (32, 8). LDS 50 KB. hi*hi + hi*lo + lo*hi (err ~2^-17).
// ---------------------------------------------------------------------------
__global__ __launch_bounds__(512) void pv_mfma_kernel(
    const float* __restrict__ st,
    const ushort* __restrict__ vthi, const ushort* __restrict__ vtlo,
    const ushort* __restrict__ qhi, const ushort* __restrict__ qlo,
    float* __restrict__ out)
{
    __shared__ ushort Ahi[64*40], Alo[64*40];    // [i][j], stride 40
    __shared__ ushort Bhi[256*40], Blo[256*40];  // [w][j], stride 40

    const int tid = threadIdx.x;
    const int i0 = blockIdx.x * 64;
    const int b  = blockIdx.y;
    const float*  stb = st   + (size_t)b * Nn * Nn;
    const ushort* vh  = vthi + (size_t)b * Ww * Nn;
    const ushort* vl  = vtlo + (size_t)b * Ww * Nn;

    const int wave = tid >> 6, lane = tid & 63;
    const int wy  = wave & 3;      // i 16-block (4 waves)
    const int wxw = wave >> 2;     // w 128-half (2 waves)
    const int lr = lane & 15, lg = lane >> 4;

    f32x4 acc[8];
    #pragma unroll
    for (int t = 0; t < 8; ++t) acc[t] = (f32x4){0.f, 0.f, 0.f, 0.f};

    const int ajj = tid >> 4;          // 0..31 (j within tile)
    const int aic = (tid & 15) * 4;    // i chunk
    const int bw  = tid >> 1;          // 0..255 (w row)
    const int bjc = (tid & 1) * 16;    // j chunk

    // prologue: tile 0 into registers
    float4 pA   = *(const float4*)(stb + (size_t)ajj * Nn + i0 + aic);
    bf16x8 pBh0 = *(const bf16x8*)(vh + (size_t)bw * Nn + bjc);
    bf16x8 pBh1 = *(const bf16x8*)(vh + (size_t)bw * Nn + bjc + 8);
    bf16x8 pBl0 = *(const bf16x8*)(vl + (size_t)bw * Nn + bjc);
    bf16x8 pBl1 = *(const bf16x8*)(vl + (size_t)bw * Nn + bjc + 8);

    for (int kc = 0; kc < Nn; kc += 32) {
        // write staged regs -> LDS (A: convert fp32 -> split bf16, transpose)
        {
            float pf[4] = {pA.x, pA.y, pA.z, pA.w};
            #pragma unroll
            for (int c = 0; c < 4; ++c) {
                ushort h = bf16_rne(pf[c]);
                Ahi[(aic + c) * 40 + ajj] = h;
                Alo[(aic + c) * 40 + ajj] = bf16_rne(pf[c] - bf16_to_f32(h));
            }
            *(bf16x8*)&Bhi[bw * 40 + bjc]     = pBh0;
            *(bf16x8*)&Bhi[bw * 40 + bjc + 8] = pBh1;
            *(bf16x8*)&Blo[bw * 40 + bjc]     = pBl0;
            *(bf16x8*)&Blo[bw * 40 + bjc + 8] = pBl1;
        }
        __syncthreads();

        // issue next-tile loads (latency hidden under MFMA below)
        if (kc + 32 < Nn) {
            pA   = *(const float4*)(stb + (size_t)(kc + 32 + ajj) * Nn + i0 + aic);
            pBh0 = *(const bf16x8*)(vh + (size_t)bw * Nn + kc + 32 + bjc);
            pBh1 = *(const bf16x8*)(vh + (size_t)bw * Nn + kc + 32 + bjc + 8);
            pBl0 = *(const bf16x8*)(vl + (size_t)bw * Nn + kc + 32 + bjc);
            pBl1 = *(const bf16x8*)(vl + (size_t)bw * Nn + kc + 32 + bjc + 8);
        }

        bf16x8 a_h = *(const bf16x8*)&Ahi[(wy * 16 + lr) * 40 + lg * 8];
        bf16x8 a_l = *(const bf16x8*)&Alo[(wy * 16 + lr) * 40 + lg * 8];
        #pragma unroll
        for (int bt = 0; bt < 8; ++bt) {
            int brow = (wxw * 128 + bt * 16 + lr) * 40 + lg * 8;
            bf16x8 b_h = *(const bf16x8*)&Bhi[brow];
            bf16x8 b_l = *(const bf16x8*)&Blo[brow];
            acc[bt] = __builtin_amdgcn_mfma_f32_16x16x32_bf16(a_h, b_h, acc[bt], 0, 0, 0);
            acc[bt] = __builtin_amdgcn_mfma_f32_16x16x32_bf16(a_h, b_l, acc[bt], 0, 0, 0);
            acc[bt] = __builtin_amdgcn_mfma_f32_16x16x32_bf16(a_l, b_h, acc[bt], 0, 0, 0);
        }
        __syncthreads();
    }

    // epilogue: D row = i = wy*16 + lg*4 + reg; col = w = wxw*128 + bt*16 + lr
    #pragma unroll
    for (int bt = 0; bt < 8; ++bt) {
        int w = wxw * 128 + bt * 16 + lr;
        #pragma unroll
        for (int rg = 0; rg < 4; ++rg) {
            int i = i0 + wy * 16 + lg * 4 + rg;
            size_t gidx = ((size_t)b * Nn + i) * Ww + w;
            out[gidx] = acc[bt][rg] + bf16_to_f32(qhi[gidx]) + bf16_to_f32(qlo[gidx]);
        }
    }
}

// ---------------------------------------------------------------------------
// Launch. ws: v32 f32 [16MB] | qhi,qlo,khi,klo bf16 [4x8MB] | ST f32 [128MB]
// = 176 MiB. vT (hi/lo) REUSES the khi/klo region after scores consumed k.
// ---------------------------------------------------------------------------
extern "C" void kernel_launch(void* const* d_in, const int* in_sizes, int n_in,
                              void* d_out, int out_size, void* d_ws, size_t ws_size,
                              hipStream_t stream) {
    const float* x  = (const float*)d_in[0];
    const float* Wq = (const float*)d_in[1];
    const float* bq = (const float*)d_in[2];
    const float* Wk = (const float*)d_in[3];
    const float* bk = (const float*)d_in[4];
    const float* Wv = (const float*)d_in[5];
    const float* bv = (const float*)d_in[6];
    // d_in[7] = valid_len (unused by the reference forward)
    float* out = (float*)d_out;

    float*  v32 = (float*)d_ws;
    ushort* qhi = (ushort*)(v32 + (size_t)Mtot * Ww);
    ushort* qlo = qhi + (size_t)Mtot * Ww;
    ushort* khi = qlo + (size_t)Mtot * Ww;
    ushort* klo = khi + (size_t)Mtot * Ww;
    float*  st  = (float*)(klo + (size_t)Mtot * Ww);
    ushort* vthi = khi;   // reuse after scores_mfma consumed k
    ushort* vtlo = klo;

    qkv_proj_kernel<<<dim3(128, 12), 256, 0, stream>>>(x, Wq, bq, Wk, bk, Wv, bv,
                                                       v32, qhi, qlo, khi, klo);
    scores_mfma_kernel<<<dim3(16, 16, 8), 256, 0, stream>>>(qhi, qlo, khi, klo, st);
    vt_kernel<<<dim3(32, 4, 8), 256, 0, stream>>>(v32, vthi, vtlo);
    softmax_kernel<<<dim3(Nn, Bb), 256, 0, stream>>>(st);
    pv_mfma_kernel<<<dim3(32, 8), 512, 0, stream>>>(st, vthi, vtlo, qhi, qlo, out);
}